// Round 1
// baseline (701.939 us; speedup 1.0000x reference)
//
#include <hip/hip_runtime.h>
#include <stdint.h>
#include <math.h>

#define N_CLS    81
#define TOPK     1000
#define CAP      8192
#define HSHIFT   14
#define HSIZE    (1 << 18)
#define BIN_HI   ((int)(0x3F800000u >> HSHIFT))   // bucket of 1.0f = 65024
#define BIN_LO   ((int)(0x3D4CCCCDu >> HSHIFT))   // bucket of 0.05f = 62771
#define SCORE_TH 0.05f
#define IMG_W    1333.0f
#define IMG_H    800.0f

// workspace layout (byte offsets)
#define OFF_CNT    0          // u32 selected-count
#define OFF_THR    8          // u32 threshold score-bits
#define OFF_SORTED 64         // u64[1000] sorted keys (0 = invalid sentinel)
#define OFF_SEL    8192       // u64[CAP] compacted candidate keys
#define OFF_BOX    73728      // f32[1000*4] clipped boxes
#define OFF_SCORE  89728      // f32[1000]
#define OFF_CLS    93728      // i32[1000]
#define OFF_MASK   98304      // u64[1000*16] conflict bit matrix
#define OFF_HIST   229376     // u32[HSIZE] histogram (1 MB)
#define OFF_ROWMAX 1277952    // f32[Nrows]
#define OFF_ROWSUM 2077952    // f32[Nrows]
#define MEMSET_BYTES (OFF_HIST + HSIZE * 4)   // 1,277,952

typedef unsigned long long u64;

// ---------------- K1: softmax + histogram of candidate score bits ----------------
__global__ __launch_bounds__(256) void k_softmax_hist(
        const float* __restrict__ logits, int nrows,
        float* __restrict__ rowMax, float* __restrict__ rowSum,
        unsigned* __restrict__ hist) {
    int wave = threadIdx.x >> 6;
    int lane = threadIdx.x & 63;
    int row = blockIdx.x * 4 + wave;
    if (row >= nrows) return;
    const float* rp = logits + (size_t)row * N_CLS;
    float v0 = rp[lane];
    float v1 = (lane < N_CLS - 64) ? rp[64 + lane] : -INFINITY;
    float m = fmaxf(v0, v1);
    #pragma unroll
    for (int off = 32; off > 0; off >>= 1) m = fmaxf(m, __shfl_xor(m, off));
    float e0 = expf(v0 - m);
    float e1 = (lane < N_CLS - 64) ? expf(v1 - m) : 0.0f;
    float s = e0 + e1;
    #pragma unroll
    for (int off = 32; off > 0; off >>= 1) s += __shfl_xor(s, off);
    if (lane == 0) { rowMax[row] = m; rowSum[row] = s; }
    float p0 = e0 / s;
    float p1 = e1 / s;
    if (lane != 0 && p0 > SCORE_TH)
        atomicAdd(&hist[__float_as_uint(p0) >> HSHIFT], 1u);
    if (lane < N_CLS - 64 && p1 > SCORE_TH)
        atomicAdd(&hist[__float_as_uint(p1) >> HSHIFT], 1u);
}

// ---------------- K2: find cutoff bucket (contains the TOPK-th score) ----------------
__global__ void k_cutoff(const unsigned* __restrict__ hist, unsigned* __restrict__ thr) {
    int lane = threadIdx.x;  // blockDim = 64
    int running = 0;
    for (int base = BIN_HI; base >= BIN_LO - 63; base -= 64) {
        int bin = base - lane;                      // lane0 = highest bucket of chunk
        int cnt = (bin >= 0) ? (int)hist[bin] : 0;
        int pref = cnt;
        #pragma unroll
        for (int off = 1; off < 64; off <<= 1) {
            int v = __shfl_up(pref, off);
            if (lane >= off) pref += v;
        }
        u64 ball = __ballot(running + pref >= TOPK);
        if (ball) {
            if (lane == 0)
                *thr = (unsigned)(base - (int)__builtin_ctzll(ball)) << HSHIFT;
            return;
        }
        running += __shfl(pref, 63);
    }
    if (lane == 0) *thr = 0u;  // fewer than TOPK candidates: take everything
}

// ---------------- K3: recompute probs, compact candidates >= cutoff ----------------
__global__ __launch_bounds__(256) void k_compact(
        const float* __restrict__ logits, int nrows,
        const float* __restrict__ rowMax, const float* __restrict__ rowSum,
        const unsigned* __restrict__ thr,
        u64* __restrict__ sel, unsigned* __restrict__ cnt) {
    int wave = threadIdx.x >> 6;
    int lane = threadIdx.x & 63;
    int row = blockIdx.x * 4 + wave;
    if (row >= nrows) return;
    const float* rp = logits + (size_t)row * N_CLS;
    float m = rowMax[row];
    float s = rowSum[row];
    unsigned tb = *thr;
    float p0 = expf(rp[lane] - m) / s;
    float p1 = 0.0f;
    if (lane < N_CLS - 64) p1 = expf(rp[64 + lane] - m) / s;
    bool c0 = (lane != 0) && (p0 > SCORE_TH) && (__float_as_uint(p0) >= tb);
    bool c1 = (lane < N_CLS - 64) && (p1 > SCORE_TH) && (__float_as_uint(p1) >= tb);
    u64 b0 = __ballot(c0);
    u64 b1 = __ballot(c1);
    int n0 = __popcll(b0), n1 = __popcll(b1);
    if (n0 + n1 == 0) return;
    unsigned base = 0;
    if (lane == 0) base = atomicAdd(cnt, (unsigned)(n0 + n1));
    base = __shfl(base, 0);
    u64 lt = (1ull << lane) - 1ull;
    if (c0) {
        unsigned pos = base + (unsigned)__popcll(b0 & lt);
        if (pos < CAP)
            sel[pos] = ((u64)__float_as_uint(p0) << 32) |
                       (u64)(0xFFFFFFu - (unsigned)(row * N_CLS + lane));
    }
    if (c1) {
        unsigned pos = base + (unsigned)n0 + (unsigned)__popcll(b1 & lt);
        if (pos < CAP)
            sel[pos] = ((u64)__float_as_uint(p1) << 32) |
                       (u64)(0xFFFFFFu - (unsigned)(row * N_CLS + 64 + lane));
    }
}

// ---------------- K4: exact rank by counting (keys are distinct) ----------------
__global__ __launch_bounds__(256) void k_rank(
        const u64* __restrict__ sel, const unsigned* __restrict__ cnt,
        u64* __restrict__ sorted) {
    unsigned c = *cnt;
    int S = (int)(c < CAP ? c : CAP);
    int t = blockIdx.x * blockDim.x + threadIdx.x;
    if (t >= S) return;
    u64 my = sel[t];
    int r = 0;
    for (int j = 0; j < S; j++) r += (sel[j] > my) ? 1 : 0;
    if (r < TOPK) sorted[r] = my;
}

// ---------------- K5: decode keys, gather + clip boxes ----------------
__global__ __launch_bounds__(256) void k_decode(
        const u64* __restrict__ sorted, const float* __restrict__ boxes,
        float* __restrict__ boxK, float* __restrict__ scoreK, int* __restrict__ clsK) {
    int t = blockIdx.x * blockDim.x + threadIdx.x;
    if (t >= TOPK) return;
    u64 key = sorted[t];
    if (key != 0ull) {
        float sc = __uint_as_float((unsigned)(key >> 32));
        unsigned fi = 0xFFFFFFu - (unsigned)(key & 0xFFFFFFFFull);
        unsigned prop = fi / N_CLS;
        int cls = (int)(fi - prop * N_CLS);
        const float* b = boxes + (size_t)prop * 4;
        boxK[t * 4 + 0] = fminf(fmaxf(b[0], 0.0f), IMG_W - 1.0f);
        boxK[t * 4 + 1] = fminf(fmaxf(b[1], 0.0f), IMG_H - 1.0f);
        boxK[t * 4 + 2] = fminf(fmaxf(b[2], 0.0f), IMG_W - 1.0f);
        boxK[t * 4 + 3] = fminf(fmaxf(b[3], 0.0f), IMG_H - 1.0f);
        scoreK[t] = sc;
        clsK[t] = cls;
    } else {
        boxK[t * 4 + 0] = 0.0f; boxK[t * 4 + 1] = 0.0f;
        boxK[t * 4 + 2] = 0.0f; boxK[t * 4 + 3] = 0.0f;
        scoreK[t] = 0.0f;
        clsK[t] = -1;
    }
}

// ---------------- K6: conflict bit-matrix (IoU > 0.5 && same class) ----------------
__global__ __launch_bounds__(256) void k_conflict(
        const float* __restrict__ boxK, const int* __restrict__ clsK,
        u64* __restrict__ mask) {
    int t = blockIdx.x * blockDim.x + threadIdx.x;
    if (t >= TOPK * 16) return;
    int i = t >> 4, w = t & 15;
    float x1 = boxK[i * 4 + 0], y1 = boxK[i * 4 + 1];
    float x2 = boxK[i * 4 + 2], y2 = boxK[i * 4 + 3];
    int ci = clsK[i];
    float ai = (x2 - x1) * (y2 - y1);
    u64 m = 0;
    int jbase = w << 6;
    for (int jj = 0; jj < 64; jj++) {
        int j = jbase + jj;
        if (j >= TOPK) break;
        float u1 = boxK[j * 4 + 0], w1 = boxK[j * 4 + 1];
        float u2 = boxK[j * 4 + 2], w2 = boxK[j * 4 + 3];
        float aj = (u2 - u1) * (w2 - w1);
        float ww = fmaxf(fminf(x2, u2) - fmaxf(x1, u1), 0.0f);
        float hh = fmaxf(fminf(y2, w2) - fmaxf(y1, w1), 0.0f);
        float inter = ww * hh;
        float iou = inter / (ai + aj - inter + 1e-9f);
        if (iou > 0.5f && ci == clsK[j]) m |= (1ull << jj);
    }
    mask[(size_t)i * 16 + w] = m;
}

// ---------------- K7: sequential greedy NMS (wave 0) + output write ----------------
__global__ __launch_bounds__(1024) void k_nms_out(
        const u64* __restrict__ mask, const float* __restrict__ boxK,
        const float* __restrict__ scoreK, float* __restrict__ out) {
    __shared__ u64 lmask[4000];   // 250 rows x 16 words per chunk (32 KB)
    __shared__ u64 vmaskA[16];
    __shared__ u64 keepA[16];
    int tid = threadIdx.x;
    int wv = tid >> 6, ln = tid & 63;
    bool val = (tid < TOPK) && (scoreK[tid] > 0.0f);
    u64 bb = __ballot(val);
    if (ln == 0) vmaskA[wv] = bb;
    __syncthreads();
    u64 remv = 0, kp = 0;
    u64 vm = (wv == 0 && ln < 16) ? vmaskA[ln] : 0ull;
    for (int c = 0; c < 4; c++) {
        for (int idx = tid; idx < 4000; idx += 1024)
            lmask[idx] = mask[c * 4000 + idx];
        __syncthreads();
        if (wv == 0) {
            for (int ii = 0; ii < 250; ii++) {
                int i = c * 250 + ii;
                int w = i >> 6, bp = i & 63;
                u64 rm = __shfl(remv, w);
                u64 vv = __shfl(vm, w);
                bool keep = ((vv >> bp) & 1ull) && !((rm >> bp) & 1ull);
                if (keep) {
                    if (ln < 16) remv |= lmask[ii * 16 + ln];
                    if (ln == w) kp |= (1ull << bp);
                }
            }
        }
        __syncthreads();
    }
    if (wv == 0 && ln < 16) keepA[ln] = kp;
    __syncthreads();
    if (tid < TOPK) {
        bool k = (keepA[tid >> 6] >> (tid & 63)) & 1ull;
        float x1 = boxK[tid * 4 + 0], y1 = boxK[tid * 4 + 1];
        float x2 = boxK[tid * 4 + 2], y2 = boxK[tid * 4 + 3];
        float sc = scoreK[tid];
        out[tid * 5 + 0] = k ? x1 : 0.0f;
        out[tid * 5 + 1] = k ? y1 : 0.0f;
        out[tid * 5 + 2] = k ? x2 : 0.0f;
        out[tid * 5 + 3] = k ? y2 : 0.0f;
        out[tid * 5 + 4] = k ? sc : 0.0f;
    }
}

extern "C" void kernel_launch(void* const* d_in, const int* in_sizes, int n_in,
                              void* d_out, int out_size, void* d_ws, size_t ws_size,
                              hipStream_t stream) {
    const float* logits = (const float*)d_in[0];
    const float* boxes  = (const float*)d_in[1];
    float* out = (float*)d_out;
    int nrows = in_sizes[0] / N_CLS;   // 200000

    char* w = (char*)d_ws;
    unsigned* cnt   = (unsigned*)(w + OFF_CNT);
    unsigned* thr   = (unsigned*)(w + OFF_THR);
    u64* sorted     = (u64*)(w + OFF_SORTED);
    u64* sel        = (u64*)(w + OFF_SEL);
    float* boxK     = (float*)(w + OFF_BOX);
    float* scoreK   = (float*)(w + OFF_SCORE);
    int* clsK       = (int*)(w + OFF_CLS);
    u64* mask       = (u64*)(w + OFF_MASK);
    unsigned* hist  = (unsigned*)(w + OFF_HIST);
    float* rowMax   = (float*)(w + OFF_ROWMAX);
    float* rowSum   = (float*)(w + OFF_ROWSUM);

    hipMemsetAsync(w, 0, MEMSET_BYTES, stream);

    int rowBlocks = (nrows + 3) / 4;
    k_softmax_hist<<<rowBlocks, 256, 0, stream>>>(logits, nrows, rowMax, rowSum, hist);
    k_cutoff<<<1, 64, 0, stream>>>(hist, thr);
    k_compact<<<rowBlocks, 256, 0, stream>>>(logits, nrows, rowMax, rowSum, thr, sel, cnt);
    k_rank<<<CAP / 256, 256, 0, stream>>>(sel, cnt, sorted);
    k_decode<<<(TOPK + 255) / 256, 256, 0, stream>>>(sorted, boxes, boxK, scoreK, clsK);
    k_conflict<<<(TOPK * 16 + 255) / 256, 256, 0, stream>>>(boxK, clsK, mask);
    k_nms_out<<<1, 1024, 0, stream>>>(mask, boxK, scoreK, out);
}

// Round 2
// 213.555 us; speedup vs baseline: 3.2869x; 3.2869x over previous
//
#include <hip/hip_runtime.h>
#include <stdint.h>
#include <math.h>

#define N_CLS    81
#define TOPK     1000
#define LISTCAP  (1u << 21)     // 2M candidate keys (16 MB)
#define CAP2     16384          // final selection capacity
#define SCORE_TH 0.05f
#define IMG_W    1333.0f
#define IMG_H    800.0f
#define GH_REP   8              // coarse-hist replicas (atomic spread)

// coarse bucket = float_bits >> 19, range for (0.05, 1.0] is [1961, 2032]
#define GH_BASE  1905           // ghist index = (bits>>19) - GH_BASE, in [56,127]

// workspace layout (byte offsets)
#define OFF_CNT    0                       // u32 total candidates
#define OFF_CNT2   8                       // u32 selected count
#define OFF_GH     64                      // u32[GH_REP][128] coarse hist (4096 B)
#define OFF_RH     4608                    // u32[1024] refined hist (4096 B)
#define OFF_SORTED 8704                    // u64[1000] sorted keys (0 sentinel)
#define MEMSET_BYTES 16704
#define OFF_SEL    16768                   // u64[LISTCAP]
#define OFF_SEL2   16793984                // u64[CAP2]
#define OFF_BOX    16925056                // f32[1000*4]
#define OFF_SCORE  16941056                // f32[1000]
#define OFF_CLS    16945056                // i32[1000]
#define OFF_MASK   16949056                // u64[1000*16] conflict bit matrix

typedef unsigned long long u64;

// ------- K1: single pass: softmax, coarse hist (LDS), compact all p>0.05 -------
__global__ __launch_bounds__(256) void k_pass1(
        const float* __restrict__ logits, int nrows,
        u64* __restrict__ sel, unsigned* __restrict__ cnt,
        unsigned* __restrict__ ghist) {
    __shared__ unsigned lh[128];
    __shared__ u64 cbuf[2048];
    __shared__ unsigned lcnt, gbase;
    int tid = threadIdx.x, wv = tid >> 6, ln = tid & 63;
    for (int i = tid; i < 128; i += 256) lh[i] = 0;
    if (tid == 0) lcnt = 0;
    __syncthreads();

    int stride = gridDim.x * 16;
    for (int base = blockIdx.x * 16 + wv * 4; base < nrows; base += stride) {
        int nr = nrows - base; if (nr > 4) nr = 4;   // wave-uniform
        float v0[4], v1[4], m[4], e0[4], e1[4], s[4];
        #pragma unroll
        for (int k = 0; k < 4; k++) {
            bool ok = (k < nr);
            const float* rp = logits + (size_t)(ok ? base + k : base) * N_CLS;
            v0[k] = ok ? rp[ln] : 0.0f;
            v1[k] = (ok && ln < N_CLS - 64) ? rp[64 + ln] : -INFINITY;
        }
        #pragma unroll
        for (int k = 0; k < 4; k++) m[k] = fmaxf(v0[k], v1[k]);
        #pragma unroll
        for (int off = 32; off > 0; off >>= 1)
            #pragma unroll
            for (int k = 0; k < 4; k++) m[k] = fmaxf(m[k], __shfl_xor(m[k], off));
        #pragma unroll
        for (int k = 0; k < 4; k++) {
            e0[k] = expf(v0[k] - m[k]);
            e1[k] = (ln < N_CLS - 64) ? expf(v1[k] - m[k]) : 0.0f;
            s[k] = e0[k] + e1[k];
        }
        #pragma unroll
        for (int off = 32; off > 0; off >>= 1)
            #pragma unroll
            for (int k = 0; k < 4; k++) s[k] += __shfl_xor(s[k], off);

        #pragma unroll
        for (int k = 0; k < 4; k++) {
            if (k >= nr) break;                     // wave-uniform
            float p0 = e0[k] / s[k];
            float p1 = e1[k] / s[k];
            bool c0 = (k < nr) && (ln != 0) && (p0 > SCORE_TH);
            bool c1 = (k < nr) && (ln < N_CLS - 64) && (p1 > SCORE_TH);
            unsigned fb0 = __float_as_uint(p0), fb1 = __float_as_uint(p1);
            if (c0) atomicAdd(&lh[(fb0 >> 19) - GH_BASE], 1u);
            if (c1) atomicAdd(&lh[(fb1 >> 19) - GH_BASE], 1u);
            u64 b0 = __ballot(c0), b1 = __ballot(c1);
            int n0 = __popcll(b0), n1 = __popcll(b1);
            if (n0 + n1 == 0) continue;
            unsigned wb = 0;
            if (ln == 0) wb = atomicAdd(&lcnt, (unsigned)(n0 + n1));
            wb = __shfl(wb, 0);
            u64 lt = (1ull << ln) - 1ull;
            unsigned flat = (unsigned)(base + k) * N_CLS + (unsigned)ln;
            if (c0) {
                unsigned pos = wb + (unsigned)__popcll(b0 & lt);
                u64 key = ((u64)fb0 << 32) | (u64)(0xFFFFFFu - flat);
                if (pos < 2048) cbuf[pos] = key;
                else { unsigned gp = atomicAdd(cnt, 1u); if (gp < LISTCAP) sel[gp] = key; }
            }
            if (c1) {
                unsigned pos = wb + (unsigned)n0 + (unsigned)__popcll(b1 & lt);
                u64 key = ((u64)fb1 << 32) | (u64)(0xFFFFFFu - (flat + 64u));
                if (pos < 2048) cbuf[pos] = key;
                else { unsigned gp = atomicAdd(cnt, 1u); if (gp < LISTCAP) sel[gp] = key; }
            }
        }
    }
    __syncthreads();
    unsigned* gh = ghist + (blockIdx.x & (GH_REP - 1)) * 128;
    for (int i = tid; i < 128; i += 256) {
        unsigned v = lh[i];
        if (v) atomicAdd(&gh[i], v);
    }
    unsigned total = lcnt; if (total > 2048u) total = 2048u;
    if (tid == 0) gbase = atomicAdd(cnt, total);
    __syncthreads();
    unsigned gb = gbase;
    for (unsigned i = tid; i < total; i += 256) {
        unsigned gp = gb + i;
        if (gp < LISTCAP) sel[gp] = cbuf[i];
    }
}

// find coarse bucket B (ghist idx) containing rank TOPK; returns -1 if total<TOPK.
// *c_above = count strictly above bucket B.
__device__ inline int scan_coarse(const unsigned* __restrict__ ghist, unsigned* c_above) {
    unsigned cum = 0;
    for (int i = 127; i >= 0; --i) {
        unsigned c = 0;
        #pragma unroll
        for (int r = 0; r < GH_REP; r++) c += ghist[r * 128 + i];
        if (cum + c >= TOPK) { *c_above = cum; return i; }
        cum += c;
    }
    *c_above = cum;
    return -1;
}

// ------- K2: refined 1024-bin hist (shift 9) inside the coarse bucket -------
__global__ __launch_bounds__(256) void k_refine(
        const u64* __restrict__ sel, const unsigned* __restrict__ cnt,
        const unsigned* __restrict__ ghist, unsigned* __restrict__ rhist) {
    __shared__ unsigned lh[1024];
    __shared__ int sB;
    int tid = threadIdx.x;
    for (int i = tid; i < 1024; i += 256) lh[i] = 0;
    if (tid == 0) { unsigned ca; sB = scan_coarse(ghist, &ca); }
    __syncthreads();
    int B = sB;
    if (B < 0) return;   // fewer than TOPK candidates total
    unsigned Bbits = (unsigned)(B + GH_BASE);
    unsigned M = *cnt; if (M > LISTCAP) M = LISTCAP;
    unsigned stride = gridDim.x * blockDim.x;
    for (unsigned i = blockIdx.x * blockDim.x + tid; i < M; i += stride) {
        unsigned bits = (unsigned)(sel[i] >> 32);
        if ((bits >> 19) == Bbits) atomicAdd(&lh[(bits >> 9) & 1023u], 1u);
    }
    __syncthreads();
    for (int i = tid; i < 1024; i += 256) {
        unsigned v = lh[i];
        if (v) atomicAdd(&rhist[i], v);
    }
}

// ------- K3: compute exact threshold tb, compact keys >= tb into sel2 -------
__global__ __launch_bounds__(256) void k_select(
        const u64* __restrict__ sel, const unsigned* __restrict__ cnt,
        const unsigned* __restrict__ ghist, const unsigned* __restrict__ rhist,
        u64* __restrict__ sel2, unsigned* __restrict__ cnt2) {
    __shared__ unsigned s4[256];
    __shared__ unsigned tbs;
    int tid = threadIdx.x, ln = tid & 63;
    unsigned ps = 0;
    #pragma unroll
    for (int k = 0; k < 4; k++) ps += rhist[tid * 4 + k];
    s4[tid] = ps;
    __syncthreads();
    if (tid == 0) {
        unsigned c_above;
        int B = scan_coarse(ghist, &c_above);
        unsigned tb = 0;
        if (B >= 0) {
            unsigned cab = c_above;
            int g = -1;
            for (int i = 255; i >= 0; --i) {
                if (cab + s4[i] >= TOPK) { g = i; break; }
                cab += s4[i];
            }
            int sb = 0;
            if (g >= 0) {
                for (int i = g * 4 + 3; i >= g * 4; --i) {
                    unsigned c = rhist[i];
                    if (cab + c >= TOPK) { sb = i; break; }
                    cab += c;
                }
            }
            tb = ((unsigned)(B + GH_BASE) << 19) | ((unsigned)sb << 9);
        }
        tbs = tb;
    }
    __syncthreads();
    unsigned tb = tbs;
    unsigned M = *cnt; if (M > LISTCAP) M = LISTCAP;
    unsigned stride = gridDim.x * blockDim.x;
    for (unsigned ibase = blockIdx.x * blockDim.x; ibase < M; ibase += stride) {
        unsigned i = ibase + tid;
        bool act = (i < M);
        u64 key = act ? sel[i] : 0ull;
        bool c = act && ((unsigned)(key >> 32) >= tb);
        u64 b = __ballot(c);
        int n = __popcll(b);
        if (n == 0) continue;
        unsigned wb = 0;
        if (ln == 0) wb = atomicAdd(cnt2, (unsigned)n);
        wb = __shfl(wb, 0);
        if (c) {
            unsigned pos = wb + (unsigned)__popcll(b & ((1ull << ln) - 1ull));
            if (pos < CAP2) sel2[pos] = key;
        }
    }
}

// ------- K4: exact rank by counting (keys distinct), scatter to sorted -------
__global__ __launch_bounds__(256) void k_rank(
        const u64* __restrict__ sel2, const unsigned* __restrict__ cnt2,
        u64* __restrict__ sorted) {
    __shared__ u64 ch[2048];
    unsigned S = *cnt2; if (S > CAP2) S = CAP2;
    if (blockIdx.x * 256u >= S) return;
    unsigned t = blockIdx.x * 256u + threadIdx.x;
    u64 my = (t < S) ? sel2[t] : 0ull;
    int r = 0;
    for (unsigned c0 = 0; c0 < S; c0 += 2048) {
        unsigned n = S - c0; if (n > 2048) n = 2048;
        __syncthreads();
        for (unsigned i = threadIdx.x; i < n; i += 256) ch[i] = sel2[c0 + i];
        __syncthreads();
        if (t < S)
            for (unsigned j = 0; j < n; j++) r += (ch[j] > my) ? 1 : 0;
    }
    if (t < S && r < TOPK) sorted[r] = my;
}

// ------- K5: decode keys, gather + clip boxes -------
__global__ __launch_bounds__(256) void k_decode(
        const u64* __restrict__ sorted, const float* __restrict__ boxes,
        float* __restrict__ boxK, float* __restrict__ scoreK, int* __restrict__ clsK) {
    int t = blockIdx.x * blockDim.x + threadIdx.x;
    if (t >= TOPK) return;
    u64 key = sorted[t];
    if (key != 0ull) {
        float sc = __uint_as_float((unsigned)(key >> 32));
        unsigned fi = 0xFFFFFFu - (unsigned)(key & 0xFFFFFFFFull);
        unsigned prop = fi / N_CLS;
        int cls = (int)(fi - prop * N_CLS);
        const float* b = boxes + (size_t)prop * 4;
        boxK[t * 4 + 0] = fminf(fmaxf(b[0], 0.0f), IMG_W - 1.0f);
        boxK[t * 4 + 1] = fminf(fmaxf(b[1], 0.0f), IMG_H - 1.0f);
        boxK[t * 4 + 2] = fminf(fmaxf(b[2], 0.0f), IMG_W - 1.0f);
        boxK[t * 4 + 3] = fminf(fmaxf(b[3], 0.0f), IMG_H - 1.0f);
        scoreK[t] = sc;
        clsK[t] = cls;
    } else {
        boxK[t * 4 + 0] = 0.0f; boxK[t * 4 + 1] = 0.0f;
        boxK[t * 4 + 2] = 0.0f; boxK[t * 4 + 3] = 0.0f;
        scoreK[t] = 0.0f;
        clsK[t] = -1;
    }
}

// ------- K6: conflict bit-matrix (IoU > 0.5 && same class) -------
__global__ __launch_bounds__(256) void k_conflict(
        const float* __restrict__ boxK, const int* __restrict__ clsK,
        u64* __restrict__ mask) {
    int t = blockIdx.x * blockDim.x + threadIdx.x;
    if (t >= TOPK * 16) return;
    int i = t >> 4, w = t & 15;
    float x1 = boxK[i * 4 + 0], y1 = boxK[i * 4 + 1];
    float x2 = boxK[i * 4 + 2], y2 = boxK[i * 4 + 3];
    int ci = clsK[i];
    float ai = (x2 - x1) * (y2 - y1);
    u64 m = 0;
    int jbase = w << 6;
    for (int jj = 0; jj < 64; jj++) {
        int j = jbase + jj;
        if (j >= TOPK) break;
        float u1 = boxK[j * 4 + 0], w1 = boxK[j * 4 + 1];
        float u2 = boxK[j * 4 + 2], w2 = boxK[j * 4 + 3];
        float aj = (u2 - u1) * (w2 - w1);
        float ww = fmaxf(fminf(x2, u2) - fmaxf(x1, u1), 0.0f);
        float hh = fmaxf(fminf(y2, w2) - fmaxf(y1, w1), 0.0f);
        float inter = ww * hh;
        float iou = inter / (ai + aj - inter + 1e-9f);
        if (iou > 0.5f && ci == clsK[j]) m |= (1ull << jj);
    }
    mask[(size_t)i * 16 + w] = m;
}

// ------- K7: Jacobi fixed-point of the triangular greedy-NMS recurrence -------
// keep[i] = valid[i] & !OR_{j<i}(keep[j] & conflict[j][i]); unique fixed point.
__global__ __launch_bounds__(1024) void k_nms_out(
        const u64* __restrict__ mask, const float* __restrict__ boxK,
        const float* __restrict__ scoreK, float* __restrict__ out) {
    __shared__ u64 words[16];
    __shared__ int changed;
    int tid = threadIdx.x, wv = tid >> 6, ln = tid & 63;
    bool valid = (tid < TOPK) && (scoreK[tid] > 0.0f);
    u64 row[16];
    #pragma unroll
    for (int w = 0; w < 16; w++)
        row[w] = (tid < TOPK) ? mask[(size_t)tid * 16 + w] : 0ull;
    u64 lowmask = (1ull << ln) - 1ull;
    bool keep = valid;
    for (int it = 0; it < 1024; ++it) {
        u64 b = __ballot(keep);
        if (ln == 0) words[wv] = b;
        if (tid == 0) changed = 0;
        __syncthreads();
        u64 sup = 0;
        for (int w = 0; w <= wv; w++) {          // wv is wave-uniform
            u64 kw = words[w];
            if (w == wv) kw &= lowmask;
            sup |= row[w] & kw;
        }
        bool nk = valid && (sup == 0ull);
        if (nk != keep) changed = 1;
        keep = nk;
        __syncthreads();
        if (!changed) break;
    }
    if (tid < TOPK) {
        float x1 = boxK[tid * 4 + 0], y1 = boxK[tid * 4 + 1];
        float x2 = boxK[tid * 4 + 2], y2 = boxK[tid * 4 + 3];
        float sc = scoreK[tid];
        out[tid * 5 + 0] = keep ? x1 : 0.0f;
        out[tid * 5 + 1] = keep ? y1 : 0.0f;
        out[tid * 5 + 2] = keep ? x2 : 0.0f;
        out[tid * 5 + 3] = keep ? y2 : 0.0f;
        out[tid * 5 + 4] = keep ? sc : 0.0f;
    }
}

extern "C" void kernel_launch(void* const* d_in, const int* in_sizes, int n_in,
                              void* d_out, int out_size, void* d_ws, size_t ws_size,
                              hipStream_t stream) {
    const float* logits = (const float*)d_in[0];
    const float* boxes  = (const float*)d_in[1];
    float* out = (float*)d_out;
    int nrows = in_sizes[0] / N_CLS;   // 200000

    char* w = (char*)d_ws;
    unsigned* cnt    = (unsigned*)(w + OFF_CNT);
    unsigned* cnt2   = (unsigned*)(w + OFF_CNT2);
    unsigned* ghist  = (unsigned*)(w + OFF_GH);
    unsigned* rhist  = (unsigned*)(w + OFF_RH);
    u64* sorted      = (u64*)(w + OFF_SORTED);
    u64* sel         = (u64*)(w + OFF_SEL);
    u64* sel2        = (u64*)(w + OFF_SEL2);
    float* boxK      = (float*)(w + OFF_BOX);
    float* scoreK    = (float*)(w + OFF_SCORE);
    int* clsK        = (int*)(w + OFF_CLS);
    u64* mask        = (u64*)(w + OFF_MASK);

    hipMemsetAsync(w, 0, MEMSET_BYTES, stream);

    k_pass1<<<1024, 256, 0, stream>>>(logits, nrows, sel, cnt, ghist);
    k_refine<<<256, 256, 0, stream>>>(sel, cnt, ghist, rhist);
    k_select<<<256, 256, 0, stream>>>(sel, cnt, ghist, rhist, sel2, cnt2);
    k_rank<<<CAP2 / 256, 256, 0, stream>>>(sel2, cnt2, sorted);
    k_decode<<<(TOPK + 255) / 256, 256, 0, stream>>>(sorted, boxes, boxK, scoreK, clsK);
    k_conflict<<<(TOPK * 16 + 255) / 256, 256, 0, stream>>>(boxK, clsK, mask);
    k_nms_out<<<1, 1024, 0, stream>>>(mask, boxK, scoreK, out);
}